// Round 5
// baseline (171.434 us; speedup 1.0000x reference)
//
#include <hip/hip_runtime.h>

#define BATCH 4
#define CH    256
#define DQ    32
#define NPIX  4096
#define LOG2E 1.44269504088896340736f

typedef unsigned short u16;
typedef unsigned int   u32;
typedef __attribute__((ext_vector_type(8))) short short8;
typedef __attribute__((ext_vector_type(16))) float f32x16;

// W pre-converted to A-frag-swizzled split-bf16: [jt][hi/lo][kk][half][j][e8]
__device__ __align__(16) u16 g_wbf[10 * 2 * 8192];
__device__ float g_bias[10 * 32];

__device__ __forceinline__ float b2f(u32 u) {
  union { u32 i; float f; } v; v.i = (u & 0xffffu) << 16; return v.f;
}
__device__ __forceinline__ u16 f2b(float f) {            // RNE fp32->bf16
  union { float f; u32 i; } v; v.f = f;
  u32 x = v.i; x += 0x7fffu + ((x >> 16) & 1u);
  return (u16)(x >> 16);
}
__device__ __forceinline__ float fexp2(float x) {
#if __has_builtin(__builtin_amdgcn_exp2f)
  return __builtin_amdgcn_exp2f(x);
#else
  return __expf(x * 0.69314718055994530942f);
#endif
}
// packed RNE fp32x2 -> bf16x2 (low = a, high = b); T12 recipe (no builtin)
__device__ __forceinline__ u32 cvtpk_bf16(float a, float b) {
  u32 r;
  asm("v_cvt_pk_bf16_f32 %0, %1, %2" : "=v"(r) : "v"(a), "v"(b));
  return r;
}
// async global->LDS, 16B per lane.  LDS dest = wave-uniform base + lane*16.
__device__ __forceinline__ void gload_lds16(const u16* gsrc, u16* ldst) {
  __builtin_amdgcn_global_load_lds(
      (const __attribute__((address_space(1))) void*)gsrc,
      (__attribute__((address_space(3))) void*)ldst, 16, 0, 0);
}

// C->B-operand half-wave exchange for the P tile (HW-verified r1-r4: pass).
__device__ __forceinline__ void half_swap(u32 a0, u32 a1, u32 b0, u32 b1,
                                          int hl, uint4& o) {
#if __has_builtin(__builtin_amdgcn_permlane32_swap)
  const auto r0 = __builtin_amdgcn_permlane32_swap((int)a0, (int)b0, false, false);
  const auto r1 = __builtin_amdgcn_permlane32_swap((int)a1, (int)b1, false, false);
  o.x = (u32)r0[0]; o.y = (u32)r1[0]; o.z = (u32)r0[1]; o.w = (u32)r1[1];
#else
  const u32 s0 = hl ? a0 : b0;
  const u32 s1 = hl ? a1 : b1;
  const u32 r0 = (u32)__shfl_xor((int)s0, 32);
  const u32 r1 = (u32)__shfl_xor((int)s1, 32);
  o.x = hl ? r0 : a0; o.y = hl ? r1 : a1;
  o.z = hl ? b0 : r0; o.w = hl ? b1 : r1;
#endif
}

// ---------------------------------------------------------------------------
// xprep (+fused wprep on the z==BATCH slice) — unchanged from r2.
// ---------------------------------------------------------------------------
__global__ __launch_bounds__(256) void xprep(
    const float* __restrict__ x, u16* __restrict__ xt_hi, u16* __restrict__ xt_lo,
    const float* __restrict__ Wq, const float* __restrict__ bq,
    const float* __restrict__ Wk, const float* __restrict__ bk,
    const float* __restrict__ Wv, const float* __restrict__ bv)
{
  const int t = threadIdx.x;

  if (blockIdx.z == BATCH) {                   // ---- wprep role ----
    if (blockIdx.y != 0 || blockIdx.x >= 10) return;
    const int jt = blockIdx.x;
    const float* Wsrc; const float* bsrc; int jrow0; float scale = 1.f;
    if (jt == 0)      { Wsrc = Wq; bsrc = bq; jrow0 = 0; scale = LOG2E; }
    else if (jt == 1) { Wsrc = Wk; bsrc = bk; jrow0 = 0; }
    else              { Wsrc = Wv; bsrc = bv; jrow0 = (jt - 2) * 32; }
    u16* wdst = g_wbf + (size_t)jt * 16384;
    for (int i = 0; i < 32; ++i) {
      const int flat = i * 256 + t;
      const int j = flat >> 8, e = flat & 255;
      const float v = Wsrc[(size_t)(jrow0 + j) * CH + e] * scale;
      const u16 hi = f2b(v);
      const u16 lo = f2b(v - b2f(hi));
      const int idx = (((e >> 4) * 2 + ((e >> 3) & 1)) * 32 + j) * 8 + (e & 7);
      wdst[idx] = hi; wdst[8192 + idx] = lo;
    }
    if (t < 32) g_bias[jt * 32 + t] = bsrc[jrow0 + t] * scale;
    return;
  }

  // ---- xprep role ----
  const int nt = blockIdx.x, kb4 = blockIdx.y * 4, b = blockIdx.z;
  const int n0 = nt * 128, c0 = blockIdx.y * 64;
  __shared__ u32 xls[64][129];                 // [c local][n local], hi | lo<<16

  const int tn = t & 127, cp = t >> 7;
  for (int i = 0; i < 32; ++i) {
    const int c = cp + 2 * i;
    const float v = x[((size_t)b * CH + c0 + c) * NPIX + n0 + tn];
    const u16 h = f2b(v);
    const u16 l = f2b(v - b2f(h));
    xls[c][tn] = (u32)h | ((u32)l << 16);
  }
  __syncthreads();

  for (int rep = 0; rep < 4; ++rep) {
    const int id = t + 256 * rep;              // 0..1023
    const int kkhl = id >> 7, n = id & 127;    // kkhl = (kk4*2 + hl)
    union { short8 s; uint4 u; } vh, vl;
    #pragma unroll
    for (int j = 0; j < 8; ++j) {
      const u32 p = xls[kkhl * 8 + j][n];
      vh.s[j] = (short)(p & 0xffffu);
      vl.s[j] = (short)(p >> 16);
    }
    const size_t o = ((((size_t)(b * 32 + nt) * 16 + kb4 + (kkhl >> 1)) * 2
                       + (kkhl & 1)) * 128 + n) * 8;
    *(uint4*)(xt_hi + o) = vh.u;
    *(uint4*)(xt_lo + o) = vl.u;
  }
}

// ---------------------------------------------------------------------------
// proj — unchanged from r2 (barrier-free, LDS-free, XCD-affine).
// ---------------------------------------------------------------------------
__global__ __launch_bounds__(256, 4) void proj(
    const u16* __restrict__ xt_hi, const u16* __restrict__ xt_lo,
    u16* __restrict__ q_t, u16* __restrict__ k_t, u16* __restrict__ v_swz)
{
  const int L = blockIdx.x;
  const int xcd = L & 7, s = L >> 3;           // s in [0,160)
  const int jt = s >> 4;                       // 0..9
  const int pair = xcd * 16 + (s & 15);        // 0..127 (nt,b)
  const int nt = pair >> 2, b = pair & 3;

  const int t = threadIdx.x;
  const int w = t >> 6, lane = t & 63, hl = lane >> 5, l31 = lane & 31;
  const int nb = w * 32 + l31, n = nt * 128 + nb;

  const u16* __restrict__ wb = g_wbf + (size_t)jt * 16384;
  const size_t xtile = (size_t)(b * 32 + nt) * 16 * 2 * 128 * 8;
  const u16* __restrict__ xh = xt_hi + xtile;
  const u16* __restrict__ xl = xt_lo + xtile;

  f32x16 acc1, acc2;
  #pragma unroll
  for (int r = 0; r < 16; ++r) { acc1[r] = 0.f; acc2[r] = 0.f; }

  #pragma unroll
  for (int kk = 0; kk < 16; ++kk) {
    const int aoff = ((kk * 2 + hl) * 32 + l31) * 8;
    const short8 wah = *(const short8*)(wb + aoff);
    const short8 wal = *(const short8*)(wb + 8192 + aoff);
    const int boff = ((kk * 2 + hl) * 128 + nb) * 8;
    const short8 xbh = *(const short8*)(xh + boff);
    const short8 xbl = *(const short8*)(xl + boff);
    acc1 = __builtin_amdgcn_mfma_f32_32x32x16_bf16(wah, xbh, acc1, 0, 0, 0);
    acc2 = __builtin_amdgcn_mfma_f32_32x32x16_bf16(wah, xbl, acc2, 0, 0, 0);
    acc2 = __builtin_amdgcn_mfma_f32_32x32x16_bf16(wal, xbh, acc2, 0, 0, 0);
  }

  f32x16 accv;
  #pragma unroll
  for (int r = 0; r < 16; ++r)
    accv[r] = acc1[r] + acc2[r]
            + g_bias[jt * 32 + (r & 3) + 8 * (r >> 2) + 4 * hl];

  if (jt <= 1) {                               // q_t / k_t: [n][d], 4x b64 stores
    u16* dst = (jt == 0) ? q_t : k_t;
    #pragma unroll
    for (int r2 = 0; r2 < 4; ++r2) {
      uint2 pk;
      pk.x = (u32)f2b(accv[4 * r2 + 0]) | ((u32)f2b(accv[4 * r2 + 1]) << 16);
      pk.y = (u32)f2b(accv[4 * r2 + 2]) | ((u32)f2b(accv[4 * r2 + 3]) << 16);
      *(uint2*)(dst + ((size_t)b * NPIX + n) * DQ + 4 * hl + 8 * r2) = pk;
    }
  } else {                                     // v_swz scatter
    const int mc = nt * 4 + w;
    const int kc = (l31 >> 4) & 1, h3 = (l31 >> 3) & 1, j8 = l31 & 7;
    u16* dst = v_swz + (((((size_t)b * 128 + mc) * 8 + (jt - 2)) * 2 + kc) * 2 + h3) * 256 + j8;
    #pragma unroll
    for (int r = 0; r < 16; ++r) {
      const int c5 = (r & 3) + 8 * (r >> 2) + 4 * hl;
      dst[c5 * 8] = f2b(accv[r]);
    }
  }
}

// ---------------------------------------------------------------------------
// attn v5: V-latency decoupling via wave-private LDS double-buffer.
// Diagnosis (r0-r4): wall = 4.3x MFMA-time with MfmaUtil ~24% under ALL of
// {2 or 4 waves/SIMD, 1x or 2x V traffic, L2-affine or not} -> waves stall
// on V L2-latency inside PV; hiding needs ~20KB in flight per SIMD, which
// VGPR-level prefetch can't reach.  Fix: each wave stages its NEXT iter's
// 8KB V-half into a private LDS buffer at iter top (8x global_load_lds
// dwordx4), computes S/exp/pack (~400cy cover), then waits vmcnt(8) -- the
// 8 newest outstanding are next-tile stages, so current tile is guaranteed
// in LDS and the pipeline NEVER drains (in-order vmcnt).  PV reads V via
// ds_read_b128 (conflict-free).  No barriers in the m-loop (wave-private
// staging).  Structure/math identical to r4 (verified): 8 waves = g(4) x
// h(2), acc[4], S redundant across h, cvt_pk, permlane swap, XCD-affine.
// LDS 128KB (1 block/CU, 2 waves/SIMD) reused as combine buffer after loop.
// grid (512), 512 thr.
// ---------------------------------------------------------------------------
__global__ __launch_bounds__(512, 2) void attn(
    const u16* __restrict__ q_t, const u16* __restrict__ k_t,
    const u16* __restrict__ v_swz, const float* __restrict__ x,
    const float* __restrict__ gamma, float* __restrict__ out)
{
  const int L = blockIdx.x;
  const int xcd = L & 7, slot = L >> 3;        // slot 0..63
  const int b = xcd >> 1;                      // XCD pair {2b,2b+1} <- batch b
  const int nt = slot * 2 + (xcd & 1);         // 0..127, bijective
  const int n0 = nt * 32;

  const int t = threadIdx.x;
  const int w = t >> 6, lane = t & 63, hl = lane >> 5, l31 = lane & 31;
  const int g = w >> 1, h = w & 1;             // m-quarter, ct-half

  __shared__ u16 smem[65536];                  // 128 KB: V dbuf, then combine
  u16* const vls = smem + w * 8192;            // this wave's 16 KB (2x4096 el)

  // Q B-frags (persistent): B[k=d][col=n=l31]
  short8 qf[2];
  #pragma unroll
  for (int kd = 0; kd < 2; ++kd)
    qf[kd] = *(const short8*)(q_t + ((size_t)b * NPIX + n0 + l31) * DQ + kd * 16 + hl * 8);

  f32x16 acc[4];
  #pragma unroll
  for (int c = 0; c < 4; ++c)
    #pragma unroll
    for (int r = 0; r < 16; ++r) acc[c][r] = 0.f;
  float lrun = 0.f;

  const u16* __restrict__ kb = k_t + (size_t)b * NPIX * DQ;
  // per-lane global source base for this wave's V half-tiles
  const u16* __restrict__ vsrc = v_swz + ((size_t)b * 128) * 8192
                                 + h * 4096 + lane * 8;

  // ---- prologue: stage tile cc=0 into buf 0 ----
  {
    const u16* s0 = vsrc + (size_t)(g * 32) * 8192;
    #pragma unroll
    for (int i = 0; i < 8; ++i) gload_lds16(s0 + i * 512, vls + i * 512);
  }

  for (int cc = 0; cc < 32; ++cc) {
    const int mc = g * 32 + cc;
    const int buf = cc & 1;

    // ---- K frags (compiler-scheduled; VGPR headroom allows hoisting) ----
    const short8 kf0 = *(const short8*)(kb + (mc * 32 + l31) * DQ + hl * 8);
    const short8 kf1 = *(const short8*)(kb + (mc * 32 + l31) * DQ + 16 + hl * 8);

    // ---- stage NEXT tile into the other buffer (8 async 1KB copies) ----
    {
      const int mcn = g * 32 + ((cc < 31) ? cc + 1 : 31);
      const u16* sn = vsrc + (size_t)mcn * 8192;
      u16* dn = vls + (buf ^ 1) * 4096;
      #pragma unroll
      for (int i = 0; i < 8; ++i) gload_lds16(sn + i * 512, dn + i * 512);
    }

    // ---- S^T = K . Q^T (redundant across the 2 ct-halves) ----
    f32x16 st;
    #pragma unroll
    for (int r = 0; r < 16; ++r) st[r] = 0.f;
    st = __builtin_amdgcn_mfma_f32_32x32x16_bf16(kf0, qf[0], st, 0, 0, 0);
    st = __builtin_amdgcn_mfma_f32_32x32x16_bf16(kf1, qf[1], st, 0, 0, 0);

    // ---- P = exp2(S), l partial, pack via cvt_pk ----
    u32 pk[4][2];
    #pragma unroll
    for (int g4 = 0; g4 < 4; ++g4) {
      const float e0 = fexp2(st[4 * g4 + 0]);
      const float e1 = fexp2(st[4 * g4 + 1]);
      const float e2 = fexp2(st[4 * g4 + 2]);
      const float e3 = fexp2(st[4 * g4 + 3]);
      lrun += (e0 + e1) + (e2 + e3);
      pk[g4][0] = cvtpk_bf16(e0, e1);
      pk[g4][1] = cvtpk_bf16(e2, e3);
    }

    // ---- current tile guaranteed in LDS: 8 newest in-flight = next-tile ----
    asm volatile("s_waitcnt vmcnt(8)" ::: "memory");
    __builtin_amdgcn_sched_barrier(0);

    // ---- PV over this wave's 4 ct tiles, V from LDS ----
    const u16* vt = vls + buf * 4096;
    #pragma unroll
    for (int kc = 0; kc < 2; ++kc) {
      union { uint4 u; short8 s; } bu;
      half_swap(pk[2 * kc][0], pk[2 * kc][1], pk[2 * kc + 1][0], pk[2 * kc + 1][1], hl, bu.u);
      #pragma unroll
      for (int c = 0; c < 4; ++c) {
        const short8 av = *(const short8*)(vt + (c * 2 + kc) * 512 + hl * 256 + l31 * 8);
        acc[c] = __builtin_amdgcn_mfma_f32_32x32x16_bf16(av, bu.s, acc[c], 0, 0, 0);
      }
    }
  }

  // ---- m-loop done; repurpose smem as combine buffers ----
  __syncthreads();                             // all waves done with V dbuf
  float* const cbuf = (float*)smem;            // 32 KB: 256 ch x 32 col
  float* const lbf  = (float*)smem + 8192;     // 1 KB: l partials [g][lane]

  if (h == 0) lbf[g * 64 + lane] = lrun;
  if (g == 0) {
    #pragma unroll
    for (int c = 0; c < 4; ++c)
      #pragma unroll
      for (int r = 0; r < 16; ++r) {
        const int ch = (h * 4 + c) * 32 + (r & 3) + 8 * (r >> 2) + 4 * hl;
        cbuf[ch * 32 + l31] = acc[c][r];
      }
  }
  for (int gs = 1; gs < 4; ++gs) {
    __syncthreads();
    if (g == gs) {
      #pragma unroll
      for (int c = 0; c < 4; ++c)
        #pragma unroll
        for (int r = 0; r < 16; ++r) {
          const int ch = (h * 4 + c) * 32 + (r & 3) + 8 * (r >> 2) + 4 * hl;
          cbuf[ch * 32 + l31] += acc[c][r];
        }
    }
  }
  __syncthreads();

  // ---- fused epilogue: 512 thr cover 32 cols x 256 ch ----
  const int col = t & 31, chg = t >> 5;        // chg 0..15
  float l = 0.f;
  #pragma unroll
  for (int gg = 0; gg < 4; ++gg)
    l += lbf[gg * 64 + col] + lbf[gg * 64 + col + 32];
  const float linv = 1.0f / l;
  const float gmv = gamma[0];
  #pragma unroll
  for (int i = 0; i < 16; ++i) {
    const int ch = chg * 16 + i;
    const float cb = cbuf[ch * 32 + col];
    const size_t oidx = ((size_t)b * CH + ch) * NPIX + n0 + col;
    out[oidx] = gmv * cb * linv + x[oidx];
  }
}

// ---------------------------------------------------------------------------
extern "C" void kernel_launch(void* const* d_in, const int* in_sizes, int n_in,
                              void* d_out, int out_size, void* d_ws, size_t ws_size,
                              hipStream_t stream) {
  const float* x  = (const float*)d_in[0];
  const float* Wq = (const float*)d_in[1];
  const float* bq = (const float*)d_in[2];
  const float* Wk = (const float*)d_in[3];
  const float* bk = (const float*)d_in[4];
  const float* Wv = (const float*)d_in[5];
  const float* bv = (const float*)d_in[6];
  const float* gm = (const float*)d_in[7];
  float* out = (float*)d_out;

  // ws: q_t 1MB | k_t 1MB | v_swz 8MB (all bf16) — 10MB
  const size_t qk_elems = (size_t)BATCH * NPIX * DQ;
  const size_t v_elems  = (size_t)BATCH * NPIX * CH;
  const size_t need = (2 * qk_elems + v_elems) * sizeof(u16);
  if (ws_size < need) return;

  u16* q_t   = (u16*)d_ws;
  u16* k_t   = q_t + qk_elems;
  u16* v_swz = k_t + qk_elems;

  // xt planes live in d_out (dead until attn's epilogue overwrites it)
  u16* xt_hi = (u16*)d_out;
  u16* xt_lo = xt_hi + (size_t)BATCH * NPIX * CH;

  xprep<<<dim3(NPIX / 128, CH / 64, BATCH + 1), 256, 0, stream>>>(
      x, xt_hi, xt_lo, Wq, bq, Wk, bk, Wv, bv);
  proj<<<dim3(32 * 10 * BATCH), 256, 0, stream>>>(xt_hi, xt_lo, q_t, k_t, v_swz);
  attn<<<dim3((NPIX / 32) * BATCH), 512, 0, stream>>>(q_t, k_t, v_swz, x, gm, out);
}

// Round 7
// 157.196 us; speedup vs baseline: 1.0906x; 1.0906x over previous
//
#include <hip/hip_runtime.h>

#define BATCH 4
#define CH    256
#define DQ    32
#define NPIX  4096
#define LOG2E 1.44269504088896340736f

typedef unsigned short u16;
typedef unsigned int   u32;
typedef __attribute__((ext_vector_type(8))) short short8;
typedef __attribute__((ext_vector_type(16))) float f32x16;

// W pre-converted to A-frag-swizzled split-bf16: [jt][hi/lo][kk][half][j][e8]
__device__ __align__(16) u16 g_wbf[10 * 2 * 8192];
__device__ float g_bias[10 * 32];

__device__ __forceinline__ float b2f(u32 u) {
  union { u32 i; float f; } v; v.i = (u & 0xffffu) << 16; return v.f;
}
__device__ __forceinline__ u16 f2b(float f) {            // RNE fp32->bf16
  union { float f; u32 i; } v; v.f = f;
  u32 x = v.i; x += 0x7fffu + ((x >> 16) & 1u);
  return (u16)(x >> 16);
}
__device__ __forceinline__ float fexp2(float x) {
#if __has_builtin(__builtin_amdgcn_exp2f)
  return __builtin_amdgcn_exp2f(x);
#else
  return __expf(x * 0.69314718055994530942f);
#endif
}
// packed RNE fp32x2 -> bf16x2 (low = a, high = b); T12 recipe (no builtin)
__device__ __forceinline__ u32 cvtpk_bf16(float a, float b) {
  u32 r;
  asm("v_cvt_pk_bf16_f32 %0, %1, %2" : "=v"(r) : "v"(a), "v"(b));
  return r;
}

// C->B-operand half-wave exchange for the P tile (HW-verified r1-r5: pass).
__device__ __forceinline__ void half_swap(u32 a0, u32 a1, u32 b0, u32 b1,
                                          int hl, uint4& o) {
#if __has_builtin(__builtin_amdgcn_permlane32_swap)
  const auto r0 = __builtin_amdgcn_permlane32_swap((int)a0, (int)b0, false, false);
  const auto r1 = __builtin_amdgcn_permlane32_swap((int)a1, (int)b1, false, false);
  o.x = (u32)r0[0]; o.y = (u32)r1[0]; o.z = (u32)r0[1]; o.w = (u32)r1[1];
#else
  const u32 s0 = hl ? a0 : b0;
  const u32 s1 = hl ? a1 : b1;
  const u32 r0 = (u32)__shfl_xor((int)s0, 32);
  const u32 r1 = (u32)__shfl_xor((int)s1, 32);
  o.x = hl ? r0 : a0; o.y = hl ? r1 : a1;
  o.z = hl ? b0 : r0; o.w = hl ? b1 : r1;
#endif
}

// ---------------------------------------------------------------------------
// xprep (+fused wprep on the z==BATCH slice) — unchanged from r2.
// ---------------------------------------------------------------------------
__global__ __launch_bounds__(256) void xprep(
    const float* __restrict__ x, u16* __restrict__ xt_hi, u16* __restrict__ xt_lo,
    const float* __restrict__ Wq, const float* __restrict__ bq,
    const float* __restrict__ Wk, const float* __restrict__ bk,
    const float* __restrict__ Wv, const float* __restrict__ bv)
{
  const int t = threadIdx.x;

  if (blockIdx.z == BATCH) {                   // ---- wprep role ----
    if (blockIdx.y != 0 || blockIdx.x >= 10) return;
    const int jt = blockIdx.x;
    const float* Wsrc; const float* bsrc; int jrow0; float scale = 1.f;
    if (jt == 0)      { Wsrc = Wq; bsrc = bq; jrow0 = 0; scale = LOG2E; }
    else if (jt == 1) { Wsrc = Wk; bsrc = bk; jrow0 = 0; }
    else              { Wsrc = Wv; bsrc = bv; jrow0 = (jt - 2) * 32; }
    u16* wdst = g_wbf + (size_t)jt * 16384;
    for (int i = 0; i < 32; ++i) {
      const int flat = i * 256 + t;
      const int j = flat >> 8, e = flat & 255;
      const float v = Wsrc[(size_t)(jrow0 + j) * CH + e] * scale;
      const u16 hi = f2b(v);
      const u16 lo = f2b(v - b2f(hi));
      const int idx = (((e >> 4) * 2 + ((e >> 3) & 1)) * 32 + j) * 8 + (e & 7);
      wdst[idx] = hi; wdst[8192 + idx] = lo;
    }
    if (t < 32) g_bias[jt * 32 + t] = bsrc[jrow0 + t] * scale;
    return;
  }

  // ---- xprep role ----
  const int nt = blockIdx.x, kb4 = blockIdx.y * 4, b = blockIdx.z;
  const int n0 = nt * 128, c0 = blockIdx.y * 64;
  __shared__ u32 xls[64][129];                 // [c local][n local], hi | lo<<16

  const int tn = t & 127, cp = t >> 7;
  for (int i = 0; i < 32; ++i) {
    const int c = cp + 2 * i;
    const float v = x[((size_t)b * CH + c0 + c) * NPIX + n0 + tn];
    const u16 h = f2b(v);
    const u16 l = f2b(v - b2f(h));
    xls[c][tn] = (u32)h | ((u32)l << 16);
  }
  __syncthreads();

  for (int rep = 0; rep < 4; ++rep) {
    const int id = t + 256 * rep;              // 0..1023
    const int kkhl = id >> 7, n = id & 127;    // kkhl = (kk4*2 + hl)
    union { short8 s; uint4 u; } vh, vl;
    #pragma unroll
    for (int j = 0; j < 8; ++j) {
      const u32 p = xls[kkhl * 8 + j][n];
      vh.s[j] = (short)(p & 0xffffu);
      vl.s[j] = (short)(p >> 16);
    }
    const size_t o = ((((size_t)(b * 32 + nt) * 16 + kb4 + (kkhl >> 1)) * 2
                       + (kkhl & 1)) * 128 + n) * 8;
    *(uint4*)(xt_hi + o) = vh.u;
    *(uint4*)(xt_lo + o) = vl.u;
  }
}

// ---------------------------------------------------------------------------
// proj — unchanged from r2 (barrier-free, LDS-free, XCD-affine).
// ---------------------------------------------------------------------------
__global__ __launch_bounds__(256, 4) void proj(
    const u16* __restrict__ xt_hi, const u16* __restrict__ xt_lo,
    u16* __restrict__ q_t, u16* __restrict__ k_t, u16* __restrict__ v_swz)
{
  const int L = blockIdx.x;
  const int xcd = L & 7, s = L >> 3;           // s in [0,160)
  const int jt = s >> 4;                       // 0..9
  const int pair = xcd * 16 + (s & 15);        // 0..127 (nt,b)
  const int nt = pair >> 2, b = pair & 3;

  const int t = threadIdx.x;
  const int w = t >> 6, lane = t & 63, hl = lane >> 5, l31 = lane & 31;
  const int nb = w * 32 + l31, n = nt * 128 + nb;

  const u16* __restrict__ wb = g_wbf + (size_t)jt * 16384;
  const size_t xtile = (size_t)(b * 32 + nt) * 16 * 2 * 128 * 8;
  const u16* __restrict__ xh = xt_hi + xtile;
  const u16* __restrict__ xl = xt_lo + xtile;

  f32x16 acc1, acc2;
  #pragma unroll
  for (int r = 0; r < 16; ++r) { acc1[r] = 0.f; acc2[r] = 0.f; }

  #pragma unroll
  for (int kk = 0; kk < 16; ++kk) {
    const int aoff = ((kk * 2 + hl) * 32 + l31) * 8;
    const short8 wah = *(const short8*)(wb + aoff);
    const short8 wal = *(const short8*)(wb + 8192 + aoff);
    const int boff = ((kk * 2 + hl) * 128 + nb) * 8;
    const short8 xbh = *(const short8*)(xh + boff);
    const short8 xbl = *(const short8*)(xl + boff);
    acc1 = __builtin_amdgcn_mfma_f32_32x32x16_bf16(wah, xbh, acc1, 0, 0, 0);
    acc2 = __builtin_amdgcn_mfma_f32_32x32x16_bf16(wah, xbl, acc2, 0, 0, 0);
    acc2 = __builtin_amdgcn_mfma_f32_32x32x16_bf16(wal, xbh, acc2, 0, 0, 0);
  }

  f32x16 accv;
  #pragma unroll
  for (int r = 0; r < 16; ++r)
    accv[r] = acc1[r] + acc2[r]
            + g_bias[jt * 32 + (r & 3) + 8 * (r >> 2) + 4 * hl];

  if (jt <= 1) {                               // q_t / k_t: [n][d], 4x b64 stores
    u16* dst = (jt == 0) ? q_t : k_t;
    #pragma unroll
    for (int r2 = 0; r2 < 4; ++r2) {
      uint2 pk;
      pk.x = (u32)f2b(accv[4 * r2 + 0]) | ((u32)f2b(accv[4 * r2 + 1]) << 16);
      pk.y = (u32)f2b(accv[4 * r2 + 2]) | ((u32)f2b(accv[4 * r2 + 3]) << 16);
      *(uint2*)(dst + ((size_t)b * NPIX + n) * DQ + 4 * hl + 8 * r2) = pk;
    }
  } else {                                     // v_swz scatter
    const int mc = nt * 4 + w;
    const int kc = (l31 >> 4) & 1, h3 = (l31 >> 3) & 1, j8 = l31 & 7;
    u16* dst = v_swz + (((((size_t)b * 128 + mc) * 8 + (jt - 2)) * 2 + kc) * 2 + h3) * 256 + j8;
    #pragma unroll
    for (int r = 0; r < 16; ++r) {
      const int c5 = (r & 3) + 8 * (r >> 2) + 4 * hl;
      dst[c5 * 8] = f2b(accv[r]);
    }
  }
}

// ---------------------------------------------------------------------------
// attn v6 (resubmit — r6 bench was an infra failure, no signal): r2
// structure with ONE edit — S-pipeline reorder.  Cycle model (recalibrated:
// 32x32x16 MFMA = ~32 cyc issue): r2's per-iter chain was K-load(~400) ->
// S-MFMA(~140) -> exp(~150) -> pack/swap -> PV, measured wall/iter/wave-slot
// ~2470 cyc vs ~1200 busy.  Edit: the body does exp/pack from LAST iter's
// st first (freeing st), then computes S(cc+1) into the SAME st registers,
// then PV(cc).  st isn't consumed until next iter's exp, so K-load + S-MFMA
// latency hides under PV + iter boundary.  Register-neutral, no unroll
// pins, no setprio, no asm waits (r1/r5 lessons).
// grid (512, XCD-affine), 256 thr.
// ---------------------------------------------------------------------------
__global__ __launch_bounds__(256, 2) void attn(
    const u16* __restrict__ q_t, const u16* __restrict__ k_t,
    const u16* __restrict__ v_swz, const float* __restrict__ x,
    const float* __restrict__ gamma, float* __restrict__ out)
{
  const int L = blockIdx.x;
  const int xcd = L & 7, slot = L >> 3;        // slot 0..63
  const int b = xcd >> 1;                      // XCD pair {2b,2b+1} <- batch b
  const int nt = slot * 2 + (xcd & 1);         // 0..127, bijective
  const int n0 = nt * 32;

  const int t = threadIdx.x;
  const int w = t >> 6, lane = t & 63, hl = lane >> 5, l31 = lane & 31;

  __shared__ float cbuf[8192];                 // 32 KB combine buffer
  __shared__ float lbuf[4][64];

  // Q B-frags (persistent): B[k=d][col=n=l31]
  short8 qf[2];
  #pragma unroll
  for (int kd = 0; kd < 2; ++kd)
    qf[kd] = *(const short8*)(q_t + ((size_t)b * NPIX + n0 + l31) * DQ + kd * 16 + hl * 8);

  f32x16 acc[8];
  #pragma unroll
  for (int ct = 0; ct < 8; ++ct)
    #pragma unroll
    for (int r = 0; r < 16; ++r) acc[ct][r] = 0.f;
  float lrun = 0.f;

  const u16* __restrict__ kb = k_t + (size_t)b * NPIX * DQ;

  // ---- prologue: st = S(0) ----
  f32x16 st;
  {
    const int mc0 = w * 32;
    const short8 kf0 = *(const short8*)(kb + (mc0 * 32 + l31) * DQ + hl * 8);
    const short8 kf1 = *(const short8*)(kb + (mc0 * 32 + l31) * DQ + 16 + hl * 8);
    #pragma unroll
    for (int r = 0; r < 16; ++r) st[r] = 0.f;
    st = __builtin_amdgcn_mfma_f32_32x32x16_bf16(kf0, qf[0], st, 0, 0, 0);
    st = __builtin_amdgcn_mfma_f32_32x32x16_bf16(kf1, qf[1], st, 0, 0, 0);
  }

  for (int cc = 0; cc < 32; ++cc) {
    const int mc = w * 32 + cc;

    // ---- P(cc) = exp2(st) (q pre-scaled by log2e), l partial, pack ----
    u32 pk[4][2];
    #pragma unroll
    for (int g = 0; g < 4; ++g) {
      const float e0 = fexp2(st[4 * g + 0]);
      const float e1 = fexp2(st[4 * g + 1]);
      const float e2 = fexp2(st[4 * g + 2]);
      const float e3 = fexp2(st[4 * g + 3]);
      lrun += (e0 + e1) + (e2 + e3);
      pk[g][0] = cvtpk_bf16(e0, e1);
      pk[g][1] = cvtpk_bf16(e2, e3);
    }

    // ---- st = S(cc+1): st regs free after exp; result not needed until
    //      next iter's exp -> K-load + MFMA latency hidden under PV ----
    {
      const int mcn = w * 32 + ((cc < 31) ? cc + 1 : 31);
      const short8 kf0 = *(const short8*)(kb + (mcn * 32 + l31) * DQ + hl * 8);
      const short8 kf1 = *(const short8*)(kb + (mcn * 32 + l31) * DQ + 16 + hl * 8);
      #pragma unroll
      for (int r = 0; r < 16; ++r) st[r] = 0.f;
      st = __builtin_amdgcn_mfma_f32_32x32x16_bf16(kf0, qf[0], st, 0, 0, 0);
      st = __builtin_amdgcn_mfma_f32_32x32x16_bf16(kf1, qf[1], st, 0, 0, 0);
    }

    // ---- PV(cc): acc[ct] += V^T(A) . P^T(B) per kc ----
    const size_t vbase = ((size_t)b * 128 + mc) * 8192;
    #pragma unroll
    for (int kc = 0; kc < 2; ++kc) {
      union { uint4 u; short8 s; } bu;
      half_swap(pk[2 * kc][0], pk[2 * kc][1], pk[2 * kc + 1][0], pk[2 * kc + 1][1], hl, bu.u);
      #pragma unroll
      for (int ct = 0; ct < 8; ++ct) {
        const short8 av = *(const short8*)(v_swz + vbase + (size_t)(((ct * 2 + kc) * 2 + hl) * 256) + l31 * 8);
        acc[ct] = __builtin_amdgcn_mfma_f32_32x32x16_bf16(av, bu.s, acc[ct], 0, 0, 0);
      }
    }
  }

  // ---- cross-wave additive combine (no max-sub => partials just add) ----
  lbuf[w][lane] = lrun;
  __syncthreads();
  for (int src = 1; src < 4; ++src) {
    if (w == src) {
      #pragma unroll
      for (int ct = 0; ct < 8; ++ct)
        #pragma unroll
        for (int r = 0; r < 16; ++r)
          cbuf[(ct * 16 + r) * 64 + lane] = acc[ct][r];
    }
    __syncthreads();
    if (w == 0) {
      #pragma unroll
      for (int ct = 0; ct < 8; ++ct)
        #pragma unroll
        for (int r = 0; r < 16; ++r)
          acc[ct][r] += cbuf[(ct * 16 + r) * 64 + lane];
    }
    __syncthreads();
  }

  // ---- epilogue (wave 0): out = gamma * y/l + x ----
  if (w == 0) {
    float l = (lbuf[0][lane] + lbuf[1][lane]) + (lbuf[2][lane] + lbuf[3][lane]);
    l += __shfl_xor(l, 32);                    // combine the two half-columns
    const float linv = 1.0f / l;
    const float g = gamma[0];
    #pragma unroll
    for (int ct = 0; ct < 8; ++ct)
      #pragma unroll
      for (int r = 0; r < 16; ++r) {
        const int c = ct * 32 + (r & 3) + 8 * (r >> 2) + 4 * hl;
        const size_t idx = ((size_t)b * CH + c) * NPIX + n0 + l31;
        out[idx] = g * acc[ct][r] * linv + x[idx];
      }
  }
}

// ---------------------------------------------------------------------------
extern "C" void kernel_launch(void* const* d_in, const int* in_sizes, int n_in,
                              void* d_out, int out_size, void* d_ws, size_t ws_size,
                              hipStream_t stream) {
  const float* x  = (const float*)d_in[0];
  const float* Wq = (const float*)d_in[1];
  const float* bq = (const float*)d_in[2];
  const float* Wk = (const float*)d_in[3];
  const float* bk = (const float*)d_in[4];
  const float* Wv = (const float*)d_in[5];
  const float* bv = (const float*)d_in[6];
  const float* gm = (const float*)d_in[7];
  float* out = (float*)d_out;

  // ws: q_t 1MB | k_t 1MB | v_swz 8MB (all bf16) — 10MB
  const size_t qk_elems = (size_t)BATCH * NPIX * DQ;
  const size_t v_elems  = (size_t)BATCH * NPIX * CH;
  const size_t need = (2 * qk_elems + v_elems) * sizeof(u16);
  if (ws_size < need) return;

  u16* q_t   = (u16*)d_ws;
  u16* k_t   = q_t + qk_elems;
  u16* v_swz = k_t + qk_elems;

  // xt planes live in d_out (dead until attn's epilogue overwrites it)
  u16* xt_hi = (u16*)d_out;
  u16* xt_lo = xt_hi + (size_t)BATCH * NPIX * CH;

  xprep<<<dim3(NPIX / 128, CH / 64, BATCH + 1), 256, 0, stream>>>(
      x, xt_hi, xt_lo, Wq, bq, Wk, bk, Wv, bv);
  proj<<<dim3(32 * 10 * BATCH), 256, 0, stream>>>(xt_hi, xt_lo, q_t, k_t, v_swz);
  attn<<<dim3((NPIX / 32) * BATCH), 256, 0, stream>>>(q_t, k_t, v_swz, x, gm, out);
}